// Round 2
// baseline (1142.208 us; speedup 1.0000x reference)
//
#include <hip/hip_runtime.h>
#include <hip/hip_bf16.h>

// SoftAttention fused pipeline for MI355X (gfx950).
// R4: score_gemm A-path rewritten — A fragments load DIRECTLY from global
// (feature) into registers per-lane (2x dwordx4, row=wgm*64+mi*16+cid,
// k=ks*32+quad*8), converted in-register to bf16. Eliminates the A LDS
// round-trip entirely: no 4-way-conflicted ds_writes, no A ds_reads, LDS
// 34->17.5 KB. LDS now holds only double-buffered B (glds16-staged).
// wgn-sibling waves re-read the same A rows ~simultaneously -> L1 hits.

typedef unsigned short u16;
typedef __attribute__((ext_vector_type(8))) short short8;  // 8 x bf16 (4 VGPR)
typedef __attribute__((ext_vector_type(4))) float f32x4;   // MFMA C/D frag

#define BATCH 256
#define LQ    196
#define DDIM  2048
#define ADIM  512
#define MTOT  (BATCH * LQ)   /* 50176 = 392 * 128 exactly */
#define WF_N  (BATCH * DDIM) /* 524288 */
#define KQP   1032           /* padded kq-plane stride in u16 elements */

__device__ __forceinline__ ushort4 cvt4(float4 f) {
  // Plain casts -> compiler emits v_cvt_pk_bf16_f32 (RNE).
  ushort4 r;
  r.x = __builtin_bit_cast(u16, (__bf16)f.x);
  r.y = __builtin_bit_cast(u16, (__bf16)f.y);
  r.z = __builtin_bit_cast(u16, (__bf16)f.z);
  r.w = __builtin_bit_cast(u16, (__bf16)f.w);
  return r;
}

__device__ __forceinline__ short8 cvt8(float4 a, float4 b) {
  short8 r;
  r[0] = (short)__builtin_bit_cast(u16, (__bf16)a.x);
  r[1] = (short)__builtin_bit_cast(u16, (__bf16)a.y);
  r[2] = (short)__builtin_bit_cast(u16, (__bf16)a.z);
  r[3] = (short)__builtin_bit_cast(u16, (__bf16)a.w);
  r[4] = (short)__builtin_bit_cast(u16, (__bf16)b.x);
  r[5] = (short)__builtin_bit_cast(u16, (__bf16)b.y);
  r[6] = (short)__builtin_bit_cast(u16, (__bf16)b.z);
  r[7] = (short)__builtin_bit_cast(u16, (__bf16)b.w);
  return r;
}

__device__ __forceinline__ void glds16(const u16* g, u16* l) {
  // global -> LDS direct copy, 16 B per lane; LDS dest = uniform base + lane*16
  __builtin_amdgcn_global_load_lds(
      (const __attribute__((address_space(1))) unsigned int*)g,
      (__attribute__((address_space(3))) unsigned int*)l, 16, 0, 0);
}

// ---------------- K0 (fused): blocks 0..63 prep B = W_enc^T bf16;
// blocks 64..575 att2[n][a] = b_dec+b_enc+prev_h@W_dec (split: 256 cols/blk);
// blocks 576..771 zero scores.
__global__ void prep_k(const float* __restrict__ W_enc, u16* __restrict__ Bst,
                       const float* __restrict__ prev_h,
                       const float* __restrict__ W_dec,
                       const float* __restrict__ b_dec,
                       const float* __restrict__ b_enc,
                       float* __restrict__ att2,
                       float* __restrict__ scores) {
  const int b = blockIdx.x, tid = threadIdx.x;
  __shared__ u16 smem[32 * 520];  // 33280 B; att2 path aliases 2 KB of it
  if (b < 64) {
    const int ks = b;
    for (int i4 = tid; i4 < 4096; i4 += 256) {
      int dl = i4 >> 7;
      int nn = (i4 & 127) << 2;
      float4 f = *(const float4*)(W_enc + (size_t)(ks * 32 + dl) * 512 + nn);
      *(ushort4*)(&smem[dl * 520 + nn]) = cvt4(f);
    }
    __syncthreads();
    for (int idx = tid; idx < 16384; idx += 256) {
      int kq = idx >> 12;
      int n  = (idx >> 3) & 511;
      int e  = idx & 7;
      Bst[(size_t)ks * 16384 + idx] = smem[(kq * 8 + e) * 520 + n];
    }
  } else if (b < 576) {
    const int n  = (b - 64) >> 1;
    const int c0 = ((b - 64) & 1) << 8;
    float* ph = (float*)smem;
    ph[tid]       = prev_h[n * 512 + tid];
    ph[tid + 256] = prev_h[n * 512 + tid + 256];
    __syncthreads();
    float a0 = b_dec[c0 + tid] + b_enc[c0 + tid];
    #pragma unroll 8
    for (int h = 0; h < 512; h++)
      a0 = fmaf(ph[h], W_dec[h * 512 + c0 + tid], a0);
    att2[n * 512 + c0 + tid] = a0;
  } else {
    scores[(b - 576) * 256 + tid] = 0.f;
  }
}

// ---------------- K2: pipelined MFMA GEMM + fused relu/W_tot reduce
// grid 1568 = 49 supertiles * (4 nt * 8 m); block 256 = 4 waves (2x2)
__global__ __launch_bounds__(256, 3) void score_gemm_k(
    const float* __restrict__ feature, const u16* __restrict__ Bst,
    const float* __restrict__ att2, const float* __restrict__ W_tot,
    float* __restrict__ scores) {
  __shared__ __align__(16) u16 sB[2][4 * KQP];   // [buf][kq][col=128][8]
  __shared__ float sRed[2][128];

  const int tid = threadIdx.x;
  const int b = blockIdx.x;
  // XCD swizzle: b = st*32 + nt*8 + mi8 ; XCD = b%8 = mi8 — the 4 nt
  // siblings of m-panel (st,mi8) are 8 apart (same XCD, near-simultaneous).
  const int mt = (b >> 5) * 8 + (b & 7);
  const int nt = (b >> 3) & 3;
  const int r0 = mt << 7, n0 = nt << 7;
  const int wid = tid >> 6, lane = tid & 63;
  const int wgm = wid >> 1, wgn = wid & 1;
  const int quad = lane >> 4, cid = lane & 15;

  // A direct-to-register: lane (quad,cid) of wave (wgm,wgn) covers
  // row = r0 + wgm*64 + mi*16 + cid, k = ks*32 + quad*8 .. +8  (2 float4)
  const float* gAf =
      feature + (size_t)(r0 + (wgm << 6) + cid) * 2048 + (quad << 3);

  // B staging via global_load_lds: wave w handles kq-plane w (2048 B)
  const u16* gBlane = Bst + (size_t)wid * 4096 + ((size_t)n0 << 3) + lane * 8;

  // B fragment base
  const int bbase = quad * KQP + (((wgn << 6) + cid) << 3);

  f32x4 zero = {0.f, 0.f, 0.f, 0.f};
  f32x4 acc[4][4];
  #pragma unroll
  for (int i = 0; i < 4; i++)
    #pragma unroll
    for (int j = 0; j < 4; j++) acc[i][j] = zero;

  float4 aF0, aF1, aF2, aF3, aF4, aF5, aF6, aF7;  // f32 A prefetch (1 K-step)
  // prologue: A regs + B glds for ks=0 (into buf 0)
  {
    aF0 = *(const float4*)(gAf);
    aF1 = *(const float4*)(gAf + 4);
    aF2 = *(const float4*)(gAf + 16 * 2048);
    aF3 = *(const float4*)(gAf + 16 * 2048 + 4);
    aF4 = *(const float4*)(gAf + 32 * 2048);
    aF5 = *(const float4*)(gAf + 32 * 2048 + 4);
    aF6 = *(const float4*)(gAf + 48 * 2048);
    aF7 = *(const float4*)(gAf + 48 * 2048 + 4);
    u16* dst = &sB[0][wid * KQP];
    glds16(gBlane, dst);
    glds16(gBlane + 512, dst + 512);
  }

  for (int ks = 0; ks < 64; ks++) {
    const int buf = ks & 1;
    __syncthreads();  // vmcnt(0) drain: B glds(ks) + A loads(ks) landed;
                      // all waves done reading sB[buf^1]

    // convert current A to fragments; aF regs die here and are reloaded
    short8 af[4];
    af[0] = cvt8(aF0, aF1);
    af[1] = cvt8(aF2, aF3);
    af[2] = cvt8(aF4, aF5);
    af[3] = cvt8(aF6, aF7);

    if (ks < 63) {  // prefetch ks+1 while computing ks
      const float* p = gAf + (ks + 1) * 32;
      aF0 = *(const float4*)(p);
      aF1 = *(const float4*)(p + 4);
      aF2 = *(const float4*)(p + 16 * 2048);
      aF3 = *(const float4*)(p + 16 * 2048 + 4);
      aF4 = *(const float4*)(p + 32 * 2048);
      aF5 = *(const float4*)(p + 32 * 2048 + 4);
      aF6 = *(const float4*)(p + 48 * 2048);
      aF7 = *(const float4*)(p + 48 * 2048 + 4);
      const u16* src = gBlane + (size_t)(ks + 1) * 16384;
      u16* dst = &sB[buf ^ 1][wid * KQP];
      glds16(src, dst);
      glds16(src + 512, dst + 512);
    }

    const u16* sb = &sB[buf][bbase];
    short8 bfr[4];
    #pragma unroll
    for (int ni = 0; ni < 4; ni++)
      bfr[ni] = *(const short8*)(sb + (ni << 7));
    #pragma unroll
    for (int mi = 0; mi < 4; mi++)
      #pragma unroll
      for (int ni = 0; ni < 4; ni++)
        acc[mi][ni] = __builtin_amdgcn_mfma_f32_16x16x32_bf16(
            af[mi], bfr[ni], acc[mi][ni], 0, 0, 0);
  }

  // epilogue: s[row] = sum_cols W_tot[col]*relu(acc + att2[n(row)][col])
  float wt[4];
  #pragma unroll
  for (int ni = 0; ni < 4; ni++)
    wt[ni] = W_tot[n0 + (wgn << 6) + ni * 16 + cid];

  #pragma unroll
  for (int mi = 0; mi < 4; mi++) {
    #pragma unroll
    for (int reg = 0; reg < 4; reg++) {
      int row_local = (wgm << 6) + mi * 16 + quad * 4 + reg;
      int row_flat = r0 + row_local;
      int nb = row_flat / 196;
      const float* a2r = att2 + nb * 512 + n0 + (wgn << 6);
      float s = 0.f;
      #pragma unroll
      for (int ni = 0; ni < 4; ni++) {
        float v = acc[mi][ni][reg] + a2r[ni * 16 + cid];
        s += fmaxf(v, 0.f) * wt[ni];
      }
      s += __shfl_xor(s, 1); s += __shfl_xor(s, 2);
      s += __shfl_xor(s, 4); s += __shfl_xor(s, 8);
      if (cid == 0) sRed[wgn][row_local] = s;
    }
  }
  __syncthreads();
  if (tid < 128) atomicAdd(&scores[r0 + tid], sRed[0][tid] + sRed[1][tid]);
}

// ---------------- K3: softmax over L per n
__global__ void softmax_k(const float* __restrict__ scores,
                          float* __restrict__ alpha) {
  const int n = blockIdx.x, tid = threadIdx.x;
  __shared__ float red[8];
  float s = (tid < LQ) ? scores[n * LQ + tid] : -1e30f;
  float m = s;
  for (int o = 32; o; o >>= 1) m = fmaxf(m, __shfl_xor(m, o));
  if ((tid & 63) == 0) red[tid >> 6] = m;
  __syncthreads();
  m = fmaxf(fmaxf(red[0], red[1]), fmaxf(red[2], red[3]));
  float e = (tid < LQ) ? __expf(s - m) : 0.f;
  float t = e;
  for (int o = 32; o; o >>= 1) t += __shfl_xor(t, o);
  if ((tid & 63) == 0) red[4 + (tid >> 6)] = t;
  __syncthreads();
  t = red[4] + red[5] + red[6] + red[7];
  if (tid < LQ) alpha[n * LQ + tid] = e / t;
}

// ---------------- K4: weighted_feature[n][d] = sum_l alpha[l]*feature[n][l][d]
__global__ void wsum_k(const float* __restrict__ feature,
                       const float* __restrict__ alpha,
                       float* __restrict__ out) {
  const int n = blockIdx.x >> 1, half = blockIdx.x & 1;
  const int tid = threadIdx.x;
  __shared__ float al[LQ];
  if (tid < LQ) al[tid] = alpha[n * LQ + tid];
  __syncthreads();
  const float* fp = feature + (size_t)n * LQ * DDIM + half * 1024 + tid * 4;
  float4 acc = {0.f, 0.f, 0.f, 0.f};
  #pragma unroll 8
  for (int l = 0; l < LQ; l++) {
    float a = al[l];
    float4 f = *(const float4*)(fp + (size_t)l * DDIM);
    acc.x = fmaf(a, f.x, acc.x); acc.y = fmaf(a, f.y, acc.y);
    acc.z = fmaf(a, f.z, acc.z); acc.w = fmaf(a, f.w, acc.w);
  }
  *(float4*)(out + n * DDIM + half * 1024 + tid * 4) = acc;
}

extern "C" void kernel_launch(void* const* d_in, const int* in_sizes, int n_in,
                              void* d_out, int out_size, void* d_ws, size_t ws_size,
                              hipStream_t stream) {
  const float* feature = (const float*)d_in[0];
  const float* prev_h  = (const float*)d_in[1];
  const float* W_enc   = (const float*)d_in[2];
  const float* b_enc   = (const float*)d_in[3];
  const float* W_dec   = (const float*)d_in[4];
  const float* b_dec   = (const float*)d_in[5];
  const float* W_tot   = (const float*)d_in[6];
  // d_in[7] = b_tot: softmax-invariant, unused

  float* out   = (float*)d_out;
  float* wf    = out;
  float* alpha = out + WF_N;

  char* ws = (char*)d_ws;
  u16*   Bst    = (u16*)ws;                                 // 2 MB
  float* att2   = (float*)(ws + (2u << 20));                // 512 KB
  float* scores = (float*)(ws + (2u << 20) + (512u << 10)); // 200704 B

  prep_k<<<772, 256, 0, stream>>>(W_enc, Bst, prev_h, W_dec, b_dec, b_enc,
                                  att2, scores);
  score_gemm_k<<<1568, 256, 0, stream>>>(feature, Bst, att2, W_tot, scores);
  softmax_k<<<256, 256, 0, stream>>>(scores, alpha);
  wsum_k<<<512, 256, 0, stream>>>(feature, alpha, wf);
}

// Round 3
// 934.952 us; speedup vs baseline: 1.2217x; 1.2217x over previous
//
#include <hip/hip_runtime.h>
#include <hip/hip_bf16.h>

// SoftAttention fused pipeline for MI355X (gfx950).
// R5: score_gemm with counted-vmcnt software pipeline (T3/T4-style).
// - A (feature f32): coalesced staged loads, prefetch depth 3 (reg sets),
//   cvt->LDS double-buffered.  B (bf16 pre-pack): glds16, depth 2, 4 LDS bufs.
// - One raw s_barrier per K-step preceded by s_waitcnt vmcnt(16) lgkmcnt(0):
//   retires exactly B(ks) (16 newer VMEM ops in flight by construction),
//   A prefetches never force-drained -> HBM latency hidden.
// - Main loop ks=0..60 unrolled x12 for static reg-set/buffer indices;
//   tail ks=61..63 uses plain __syncthreads (guards break constant counts).

typedef unsigned short u16;
typedef __attribute__((ext_vector_type(8))) short short8;  // 8 x bf16 (4 VGPR)
typedef __attribute__((ext_vector_type(4))) float f32x4;   // MFMA C/D frag

#define BATCH 256
#define LQ    196
#define DDIM  2048
#define ADIM  512
#define MTOT  (BATCH * LQ)   /* 50176 = 392 * 128 exactly */
#define WF_N  (BATCH * DDIM) /* 524288 */
#define KQP   1032           /* padded kq-plane stride in u16 elements */

__device__ __forceinline__ u16 bfc(float f) {
  return __builtin_bit_cast(u16, (__bf16)f);
}

__device__ __forceinline__ ushort4 cvt4(float4 f) {
  // Plain casts -> v_cvt_pk_bf16_f32 (RNE).
  ushort4 r;
  r.x = bfc(f.x); r.y = bfc(f.y); r.z = bfc(f.z); r.w = bfc(f.w);
  return r;
}

__device__ __forceinline__ void glds16(const u16* g, u16* l) {
  // global -> LDS direct copy, 16 B per lane; LDS dest = uniform base + lane*16
  __builtin_amdgcn_global_load_lds(
      (const __attribute__((address_space(1))) unsigned int*)g,
      (__attribute__((address_space(3))) unsigned int*)l, 16, 0, 0);
}

// ---------------- K0 (fused): blocks 0..63 prep B = W_enc^T bf16;
// blocks 64..575 att2[n][a] = b_dec+b_enc+prev_h@W_dec (split: 256 cols/blk);
// blocks 576..771 zero scores.
__global__ void prep_k(const float* __restrict__ W_enc, u16* __restrict__ Bst,
                       const float* __restrict__ prev_h,
                       const float* __restrict__ W_dec,
                       const float* __restrict__ b_dec,
                       const float* __restrict__ b_enc,
                       float* __restrict__ att2,
                       float* __restrict__ scores) {
  const int b = blockIdx.x, tid = threadIdx.x;
  __shared__ u16 smem[32 * 520];  // 33280 B; att2 path aliases 2 KB of it
  if (b < 64) {
    const int ks = b;
    for (int i4 = tid; i4 < 4096; i4 += 256) {
      int dl = i4 >> 7;
      int nn = (i4 & 127) << 2;
      float4 f = *(const float4*)(W_enc + (size_t)(ks * 32 + dl) * 512 + nn);
      *(ushort4*)(&smem[dl * 520 + nn]) = cvt4(f);
    }
    __syncthreads();
    for (int idx = tid; idx < 16384; idx += 256) {
      int kq = idx >> 12;
      int n  = (idx >> 3) & 511;
      int e  = idx & 7;
      Bst[(size_t)ks * 16384 + idx] = smem[(kq * 8 + e) * 520 + n];
    }
  } else if (b < 576) {
    const int n  = (b - 64) >> 1;
    const int c0 = ((b - 64) & 1) << 8;
    float* ph = (float*)smem;
    ph[tid]       = prev_h[n * 512 + tid];
    ph[tid + 256] = prev_h[n * 512 + tid + 256];
    __syncthreads();
    float a0 = b_dec[c0 + tid] + b_enc[c0 + tid];
    #pragma unroll 8
    for (int h = 0; h < 512; h++)
      a0 = fmaf(ph[h], W_dec[h * 512 + c0 + tid], a0);
    att2[n * 512 + c0 + tid] = a0;
  } else {
    scores[(b - 576) * 256 + tid] = 0.f;
  }
}

// ---------------- K2: counted-vmcnt pipelined MFMA GEMM + fused epilogue
// grid 1568 = 49 supertiles * (4 nt * 8 m); block 256 = 4 waves (2x2)
__global__ __launch_bounds__(256, 3) void score_gemm_k(
    const float* __restrict__ feature, const u16* __restrict__ Bst,
    const float* __restrict__ att2, const float* __restrict__ W_tot,
    float* __restrict__ scores) {
  __shared__ __align__(16) u16 sA[2][4 * KQP];   // [buf][kq][row=128][8]
  __shared__ __align__(16) u16 sB[4][4 * KQP];   // [buf][kq][col=128][8]
  __shared__ float sRed[2][128];

  const int tid = threadIdx.x;
  const int b = blockIdx.x;
  // XCD swizzle: b = st*32 + nt*8 + mi8 ; XCD = b%8 = mi8 — the 4 nt
  // siblings of m-panel (st,mi8) are 8 apart (same XCD, near-simultaneous).
  const int mt = (b >> 5) * 8 + (b & 7);
  const int nt = (b >> 3) & 3;
  const int r0 = mt << 7, n0 = nt << 7;
  const int wid = tid >> 6, lane = tid & 63;
  const int wgm = wid >> 1, wgn = wid & 1;
  const int quad = lane >> 4, cid = lane & 15;

  // A staging: lane reads row (tid>>3)+{0,32,64,96}, float4 #(tid&7)
  const int arow = tid >> 3, akk4 = tid & 7;
  const float* gA = feature + (size_t)(r0 + arow) * 2048 + akk4 * 4;
  const int wAoff = (akk4 >> 1) * KQP + (arow << 3) + ((akk4 & 1) << 2);

  // B staging via global_load_lds: wave w handles kq-plane w (2048 B)
  const u16* gBlane = Bst + (size_t)wid * 4096 + ((size_t)n0 << 3) + lane * 8;

  // fragment bases
  const int abase = quad * KQP + (((wgm << 6) + cid) << 3);
  const int bbase = quad * KQP + (((wgn << 6) + cid) << 3);

  f32x4 zero = {0.f, 0.f, 0.f, 0.f};
  f32x4 acc[4][4];
  #pragma unroll
  for (int i = 0; i < 4; i++)
    #pragma unroll
    for (int j = 0; j < 4; j++) acc[i][j] = zero;

  // three A-prefetch register sets (depth 3)
  float4 aS0_0, aS0_1, aS0_2, aS0_3;
  float4 aS1_0, aS1_1, aS1_2, aS1_3;
  float4 aS2_0, aS2_1, aS2_2, aS2_3;

#define LOAD_A(SET, KS) do {                                              \
    const float* p_ = gA + (size_t)(KS) * 32;                             \
    aS##SET##_0 = *(const float4*)(p_);                                   \
    aS##SET##_1 = *(const float4*)(p_ + 32 * 2048);                       \
    aS##SET##_2 = *(const float4*)(p_ + 64 * 2048);                       \
    aS##SET##_3 = *(const float4*)(p_ + 96 * 2048);                       \
  } while (0)

#define STAGE_A(SET, ABUF) do {                                           \
    u16* wa_ = &sA[ABUF][wAoff];                                          \
    *(ushort4*)(wa_)       = cvt4(aS##SET##_0);                           \
    *(ushort4*)(wa_ + 256) = cvt4(aS##SET##_1);                           \
    *(ushort4*)(wa_ + 512) = cvt4(aS##SET##_2);                           \
    *(ushort4*)(wa_ + 768) = cvt4(aS##SET##_3);                           \
  } while (0)

#define GLDS_B2(KS, BUFI) do {                                            \
    const u16* src_ = gBlane + (size_t)(KS) * 16384;                      \
    u16* dst_ = &sB[BUFI][wid * KQP];                                     \
    glds16(src_, dst_);                                                   \
    glds16(src_ + 512, dst_ + 512);                                       \
  } while (0)

#define COMPUTE(ABUF, BBUF) do {                                          \
    const u16* sa_ = &sA[ABUF][abase];                                    \
    const u16* sb_ = &sB[BBUF][bbase];                                    \
    short8 af_[4], bf_[4];                                                \
    _Pragma("unroll")                                                     \
    for (int mi = 0; mi < 4; mi++)                                        \
      af_[mi] = *(const short8*)(sa_ + (mi << 7));                        \
    _Pragma("unroll")                                                     \
    for (int ni = 0; ni < 4; ni++)                                        \
      bf_[ni] = *(const short8*)(sb_ + (ni << 7));                        \
    _Pragma("unroll")                                                     \
    for (int mi = 0; mi < 4; mi++)                                        \
      _Pragma("unroll")                                                   \
      for (int ni = 0; ni < 4; ni++)                                      \
        acc[mi][ni] = __builtin_amdgcn_mfma_f32_16x16x32_bf16(            \
            af_[mi], bf_[ni], acc[mi][ni], 0, 0, 0);                      \
  } while (0)

  // One barrier per K-step. Issue order per iter: B(ks+2) then A(ks+3).
  // FIFO after issues at iter ks: ..., B(ks), [A(ks+1)4 B(ks+1)2 A(ks+2)4
  // B(ks+2)2 A(ks+3)4] = 16 newer -> vmcnt(16) retires exactly B(ks).
#define ITER_BODY(KS, SET, ABUF, BRD, BWR) do {                           \
    STAGE_A(SET, ABUF);                                                   \
    GLDS_B2((KS) + 2, BWR);                                               \
    LOAD_A(SET, (KS) + 3);                                                \
    asm volatile("s_waitcnt vmcnt(16) lgkmcnt(0)" ::: "memory");          \
    __builtin_amdgcn_s_barrier();                                         \
    COMPUTE(ABUF, BRD);                                                   \
  } while (0)

  // prologue: B depth-2, A depth-3
  GLDS_B2(0, 0);
  GLDS_B2(1, 1);
  LOAD_A(0, 0);
  LOAD_A(1, 1);
  LOAD_A(2, 2);

  #pragma unroll 1
  for (int kb = 0; kb < 60; kb += 12) {
    ITER_BODY(kb + 0,  0, 0, 0, 2);
    ITER_BODY(kb + 1,  1, 1, 1, 3);
    ITER_BODY(kb + 2,  2, 0, 2, 0);
    ITER_BODY(kb + 3,  0, 1, 3, 1);
    ITER_BODY(kb + 4,  1, 0, 0, 2);
    ITER_BODY(kb + 5,  2, 1, 1, 3);
    ITER_BODY(kb + 6,  0, 0, 2, 0);
    ITER_BODY(kb + 7,  1, 1, 3, 1);
    ITER_BODY(kb + 8,  2, 0, 0, 2);
    ITER_BODY(kb + 9,  0, 1, 1, 3);
    ITER_BODY(kb + 10, 1, 0, 2, 0);
    ITER_BODY(kb + 11, 2, 1, 3, 1);
  }
  ITER_BODY(60, 0, 0, 0, 2);   // issues B(62)->sB[2], A(63)->set0

  // tail ks=61..63: plain __syncthreads (full drain; guards would break
  // the constant vmcnt count here). ks=61 still issues B(63)->sB[3].
  STAGE_A(1, 1); GLDS_B2(63, 3); __syncthreads(); COMPUTE(1, 1);
  STAGE_A(2, 0);                 __syncthreads(); COMPUTE(0, 2);
  STAGE_A(0, 1);                 __syncthreads(); COMPUTE(1, 3);

#undef ITER_BODY
#undef COMPUTE
#undef GLDS_B2
#undef STAGE_A
#undef LOAD_A

  // epilogue: s[row] = sum_cols W_tot[col]*relu(acc + att2[n(row)][col])
  float wt[4];
  #pragma unroll
  for (int ni = 0; ni < 4; ni++)
    wt[ni] = W_tot[n0 + (wgn << 6) + ni * 16 + cid];

  #pragma unroll
  for (int mi = 0; mi < 4; mi++) {
    #pragma unroll
    for (int reg = 0; reg < 4; reg++) {
      int row_local = (wgm << 6) + mi * 16 + quad * 4 + reg;
      int row_flat = r0 + row_local;
      int nb = row_flat / 196;
      const float* a2r = att2 + nb * 512 + n0 + (wgn << 6);
      float s = 0.f;
      #pragma unroll
      for (int ni = 0; ni < 4; ni++) {
        float v = acc[mi][ni][reg] + a2r[ni * 16 + cid];
        s += fmaxf(v, 0.f) * wt[ni];
      }
      s += __shfl_xor(s, 1); s += __shfl_xor(s, 2);
      s += __shfl_xor(s, 4); s += __shfl_xor(s, 8);
      if (cid == 0) sRed[wgn][row_local] = s;
    }
  }
  __syncthreads();
  if (tid < 128) atomicAdd(&scores[r0 + tid], sRed[0][tid] + sRed[1][tid]);
}

// ---------------- K3: softmax over L per n
__global__ void softmax_k(const float* __restrict__ scores,
                          float* __restrict__ alpha) {
  const int n = blockIdx.x, tid = threadIdx.x;
  __shared__ float red[8];
  float s = (tid < LQ) ? scores[n * LQ + tid] : -1e30f;
  float m = s;
  for (int o = 32; o; o >>= 1) m = fmaxf(m, __shfl_xor(m, o));
  if ((tid & 63) == 0) red[tid >> 6] = m;
  __syncthreads();
  m = fmaxf(fmaxf(red[0], red[1]), fmaxf(red[2], red[3]));
  float e = (tid < LQ) ? __expf(s - m) : 0.f;
  float t = e;
  for (int o = 32; o; o >>= 1) t += __shfl_xor(t, o);
  if ((tid & 63) == 0) red[4 + (tid >> 6)] = t;
  __syncthreads();
  t = red[4] + red[5] + red[6] + red[7];
  if (tid < LQ) alpha[n * LQ + tid] = e / t;
}

// ---------------- K4: weighted_feature[n][d] = sum_l alpha[l]*feature[n][l][d]
__global__ void wsum_k(const float* __restrict__ feature,
                       const float* __restrict__ alpha,
                       float* __restrict__ out) {
  const int n = blockIdx.x >> 1, half = blockIdx.x & 1;
  const int tid = threadIdx.x;
  __shared__ float al[LQ];
  if (tid < LQ) al[tid] = alpha[n * LQ + tid];
  __syncthreads();
  const float* fp = feature + (size_t)n * LQ * DDIM + half * 1024 + tid * 4;
  float4 acc = {0.f, 0.f, 0.f, 0.f};
  #pragma unroll 8
  for (int l = 0; l < LQ; l++) {
    float a = al[l];
    float4 f = *(const float4*)(fp + (size_t)l * DDIM);
    acc.x = fmaf(a, f.x, acc.x); acc.y = fmaf(a, f.y, acc.y);
    acc.z = fmaf(a, f.z, acc.z); acc.w = fmaf(a, f.w, acc.w);
  }
  *(float4*)(out + n * DDIM + half * 1024 + tid * 4) = acc;
}

extern "C" void kernel_launch(void* const* d_in, const int* in_sizes, int n_in,
                              void* d_out, int out_size, void* d_ws, size_t ws_size,
                              hipStream_t stream) {
  const float* feature = (const float*)d_in[0];
  const float* prev_h  = (const float*)d_in[1];
  const float* W_enc   = (const float*)d_in[2];
  const float* b_enc   = (const float*)d_in[3];
  const float* W_dec   = (const float*)d_in[4];
  const float* b_dec   = (const float*)d_in[5];
  const float* W_tot   = (const float*)d_in[6];
  // d_in[7] = b_tot: softmax-invariant, unused

  float* out   = (float*)d_out;
  float* wf    = out;
  float* alpha = out + WF_N;

  char* ws = (char*)d_ws;
  u16*   Bst    = (u16*)ws;                                 // 2 MB
  float* att2   = (float*)(ws + (2u << 20));                // 512 KB
  float* scores = (float*)(ws + (2u << 20) + (512u << 10)); // 200704 B

  prep_k<<<772, 256, 0, stream>>>(W_enc, Bst, prev_h, W_dec, b_dec, b_enc,
                                  att2, scores);
  score_gemm_k<<<1568, 256, 0, stream>>>(feature, Bst, att2, W_tot, scores);
  softmax_k<<<256, 256, 0, stream>>>(scores, alpha);
  wsum_k<<<512, 256, 0, stream>>>(feature, alpha, wf);
}

// Round 4
// 779.724 us; speedup vs baseline: 1.4649x; 1.1991x over previous
//
#include <hip/hip_runtime.h>
#include <hip/hip_bf16.h>

// SoftAttention fused pipeline for MI355X (gfx950).
// R6: counted-vmcnt pipeline, register-lean (R5 post-mortem: 3 A-sets +
// unroll-12 spilled to scratch -> 285MB WRITE_SIZE, 430us. Root cause was
// register pressure, not the counted-vmcnt idea).
// - A depth 2 (2 reg sets, +16 VGPR only), B glds depth 1 (2 LDS bufs).
// - Barrier = "s_waitcnt vmcnt(4) lgkmcnt(0); s_barrier": retires exactly
//   B(ks) (L2-resident Bst, 1 iter in flight, covered) while A(ks+1) stays
//   in flight across the barrier (2 iters ~1400cy > 900cy HBM latency).
// - Issue order pinned with empty memory-clobber fences so the vmcnt FIFO
//   arithmetic holds; unroll x2 keeps buffer indices static.

typedef unsigned short u16;
typedef __attribute__((ext_vector_type(8))) short short8;  // 8 x bf16 (4 VGPR)
typedef __attribute__((ext_vector_type(4))) float f32x4;   // MFMA C/D frag

#define BATCH 256
#define LQ    196
#define DDIM  2048
#define ADIM  512
#define MTOT  (BATCH * LQ)   /* 50176 = 392 * 128 exactly */
#define WF_N  (BATCH * DDIM) /* 524288 */
#define KQP   1032           /* padded kq-plane stride in u16 elements */

__device__ __forceinline__ u16 bfc(float f) {
  return __builtin_bit_cast(u16, (__bf16)f);
}

__device__ __forceinline__ ushort4 cvt4(float4 f) {
  // Plain casts -> v_cvt_pk_bf16_f32 (RNE).
  ushort4 r;
  r.x = bfc(f.x); r.y = bfc(f.y); r.z = bfc(f.z); r.w = bfc(f.w);
  return r;
}

__device__ __forceinline__ void glds16(const u16* g, u16* l) {
  // global -> LDS direct copy, 16 B per lane; LDS dest = uniform base + lane*16
  __builtin_amdgcn_global_load_lds(
      (const __attribute__((address_space(1))) unsigned int*)g,
      (__attribute__((address_space(3))) unsigned int*)l, 16, 0, 0);
}

// ---------------- K0 (fused): blocks 0..63 prep B = W_enc^T bf16;
// blocks 64..575 att2[n][a] = b_dec+b_enc+prev_h@W_dec (split: 256 cols/blk);
// blocks 576..771 zero scores.
__global__ void prep_k(const float* __restrict__ W_enc, u16* __restrict__ Bst,
                       const float* __restrict__ prev_h,
                       const float* __restrict__ W_dec,
                       const float* __restrict__ b_dec,
                       const float* __restrict__ b_enc,
                       float* __restrict__ att2,
                       float* __restrict__ scores) {
  const int b = blockIdx.x, tid = threadIdx.x;
  __shared__ u16 smem[32 * 520];  // 33280 B; att2 path aliases 2 KB of it
  if (b < 64) {
    const int ks = b;
    for (int i4 = tid; i4 < 4096; i4 += 256) {
      int dl = i4 >> 7;
      int nn = (i4 & 127) << 2;
      float4 f = *(const float4*)(W_enc + (size_t)(ks * 32 + dl) * 512 + nn);
      *(ushort4*)(&smem[dl * 520 + nn]) = cvt4(f);
    }
    __syncthreads();
    for (int idx = tid; idx < 16384; idx += 256) {
      int kq = idx >> 12;
      int n  = (idx >> 3) & 511;
      int e  = idx & 7;
      Bst[(size_t)ks * 16384 + idx] = smem[(kq * 8 + e) * 520 + n];
    }
  } else if (b < 576) {
    const int n  = (b - 64) >> 1;
    const int c0 = ((b - 64) & 1) << 8;
    float* ph = (float*)smem;
    ph[tid]       = prev_h[n * 512 + tid];
    ph[tid + 256] = prev_h[n * 512 + tid + 256];
    __syncthreads();
    float a0 = b_dec[c0 + tid] + b_enc[c0 + tid];
    #pragma unroll 8
    for (int h = 0; h < 512; h++)
      a0 = fmaf(ph[h], W_dec[h * 512 + c0 + tid], a0);
    att2[n * 512 + c0 + tid] = a0;
  } else {
    scores[(b - 576) * 256 + tid] = 0.f;
  }
}

// ---------------- K2: counted-vmcnt pipelined MFMA GEMM + fused epilogue
// grid 1568 = 49 supertiles * (4 nt * 8 m); block 256 = 4 waves (2x2)
__global__ __launch_bounds__(256, 3) void score_gemm_k(
    const float* __restrict__ feature, const u16* __restrict__ Bst,
    const float* __restrict__ att2, const float* __restrict__ W_tot,
    float* __restrict__ scores) {
  __shared__ __align__(16) u16 sA[2][4 * KQP];   // [buf][kq][row=128][8]
  __shared__ __align__(16) u16 sB[2][4 * KQP];   // [buf][kq][col=128][8]
  __shared__ float sRed[2][128];

  const int tid = threadIdx.x;
  const int b = blockIdx.x;
  // XCD swizzle: b = st*32 + nt*8 + mi8 ; XCD = b%8 = mi8 — the 4 nt
  // siblings of m-panel (st,mi8) are 8 apart (same XCD, near-simultaneous).
  const int mt = (b >> 5) * 8 + (b & 7);
  const int nt = (b >> 3) & 3;
  const int r0 = mt << 7, n0 = nt << 7;
  const int wid = tid >> 6, lane = tid & 63;
  const int wgm = wid >> 1, wgn = wid & 1;
  const int quad = lane >> 4, cid = lane & 15;

  // A staging: lane reads row (tid>>3)+{0,32,64,96}, float4 #(tid&7)
  const int arow = tid >> 3, akk4 = tid & 7;
  const float* gA = feature + (size_t)(r0 + arow) * 2048 + akk4 * 4;
  const int wAoff = (akk4 >> 1) * KQP + (arow << 3) + ((akk4 & 1) << 2);

  // B staging via global_load_lds: wave w handles kq-plane w (2048 B)
  const u16* gBlane = Bst + (size_t)wid * 4096 + ((size_t)n0 << 3) + lane * 8;

  // fragment bases
  const int abase = quad * KQP + (((wgm << 6) + cid) << 3);
  const int bbase = quad * KQP + (((wgn << 6) + cid) << 3);

  f32x4 zero = {0.f, 0.f, 0.f, 0.f};
  f32x4 acc[4][4];
  #pragma unroll
  for (int i = 0; i < 4; i++)
    #pragma unroll
    for (int j = 0; j < 4; j++) acc[i][j] = zero;

  // two A-prefetch register sets (depth 2)
  float4 aS0_0, aS0_1, aS0_2, aS0_3;
  float4 aS1_0, aS1_1, aS1_2, aS1_3;

#define FENCE asm volatile("" ::: "memory")

#define LOAD_A(SET, KS) do {                                              \
    const float* p_ = gA + (size_t)(KS) * 32;                             \
    aS##SET##_0 = *(const float4*)(p_);                                   \
    aS##SET##_1 = *(const float4*)(p_ + 32 * 2048);                       \
    aS##SET##_2 = *(const float4*)(p_ + 64 * 2048);                       \
    aS##SET##_3 = *(const float4*)(p_ + 96 * 2048);                       \
  } while (0)

#define STAGE_A(SET, ABUF) do {                                           \
    u16* wa_ = &sA[ABUF][wAoff];                                          \
    *(ushort4*)(wa_)       = cvt4(aS##SET##_0);                           \
    *(ushort4*)(wa_ + 256) = cvt4(aS##SET##_1);                           \
    *(ushort4*)(wa_ + 512) = cvt4(aS##SET##_2);                           \
    *(ushort4*)(wa_ + 768) = cvt4(aS##SET##_3);                           \
  } while (0)

#define GLDS_B(KS, BUFI) do {                                             \
    const u16* src_ = gBlane + (size_t)(KS) * 16384;                      \
    u16* dst_ = &sB[BUFI][wid * KQP];                                     \
    glds16(src_, dst_);                                                   \
    glds16(src_ + 512, dst_ + 512);                                       \
  } while (0)

#define COMPUTE(ABUF, BBUF) do {                                          \
    const u16* sa_ = &sA[ABUF][abase];                                    \
    const u16* sb_ = &sB[BBUF][bbase];                                    \
    short8 af_[4], bf_[4];                                                \
    _Pragma("unroll")                                                     \
    for (int mi = 0; mi < 4; mi++)                                        \
      af_[mi] = *(const short8*)(sa_ + (mi << 7));                        \
    _Pragma("unroll")                                                     \
    for (int ni = 0; ni < 4; ni++)                                        \
      bf_[ni] = *(const short8*)(sb_ + (ni << 7));                        \
    _Pragma("unroll")                                                     \
    for (int mi = 0; mi < 4; mi++)                                        \
      _Pragma("unroll")                                                   \
      for (int ni = 0; ni < 4; ni++)                                      \
        acc[mi][ni] = __builtin_amdgcn_mfma_f32_16x16x32_bf16(            \
            af_[mi], bf_[ni], acc[mi][ni], 0, 0, 0);                      \
  } while (0)

  // Iter ks (parity P=ks&1): STAGE_A(P->sA[P]) [compiler auto-wait retires
  // A(ks), 2 iters old]; vmcnt(4) retires exactly B(ks) [FIFO: B(ks)2 +
  // A(ks+1)4 outstanding], A(ks+1) survives the barrier; post-barrier issue
  // B(ks+1)->sB[P^1] then A(ks+2)->set P. All ds_reads of compute(ks-1)
  // completed before barrier(ks) via lgkmcnt(0) -> no WAR on sB[P^1].
#define ITER(KS, P) do {                                                  \
    STAGE_A(P, P);                                                        \
    asm volatile("s_waitcnt vmcnt(4) lgkmcnt(0)\n\ts_barrier"             \
                 ::: "memory");                                           \
    GLDS_B((KS) + 1, (P) ^ 1);                                            \
    FENCE;                                                                \
    LOAD_A(P, (KS) + 2);                                                  \
    COMPUTE(P, P);                                                        \
  } while (0)

  // prologue: B(0) -> sB[0]; A(0) -> set0, A(1) -> set1
  GLDS_B(0, 0);
  FENCE;
  LOAD_A(0, 0);
  LOAD_A(1, 1);

  #pragma unroll 1
  for (int ks = 0; ks < 62; ks += 2) {
    ITER(ks, 0);
    ITER(ks + 1, 1);
  }
  // tail iter 62: issues B(63) only (no A(64))
  STAGE_A(0, 0);
  asm volatile("s_waitcnt vmcnt(4) lgkmcnt(0)\n\ts_barrier" ::: "memory");
  GLDS_B(63, 1);
  FENCE;
  COMPUTE(0, 0);
  // tail iter 63: full drain
  STAGE_A(1, 1);
  asm volatile("s_waitcnt vmcnt(0) lgkmcnt(0)\n\ts_barrier" ::: "memory");
  COMPUTE(1, 1);

#undef ITER
#undef COMPUTE
#undef GLDS_B
#undef STAGE_A
#undef LOAD_A
#undef FENCE

  // epilogue: s[row] = sum_cols W_tot[col]*relu(acc + att2[n(row)][col])
  float wt[4];
  #pragma unroll
  for (int ni = 0; ni < 4; ni++)
    wt[ni] = W_tot[n0 + (wgn << 6) + ni * 16 + cid];

  #pragma unroll
  for (int mi = 0; mi < 4; mi++) {
    #pragma unroll
    for (int reg = 0; reg < 4; reg++) {
      int row_local = (wgm << 6) + mi * 16 + quad * 4 + reg;
      int row_flat = r0 + row_local;
      int nb = row_flat / 196;
      const float* a2r = att2 + nb * 512 + n0 + (wgn << 6);
      float s = 0.f;
      #pragma unroll
      for (int ni = 0; ni < 4; ni++) {
        float v = acc[mi][ni][reg] + a2r[ni * 16 + cid];
        s += fmaxf(v, 0.f) * wt[ni];
      }
      s += __shfl_xor(s, 1); s += __shfl_xor(s, 2);
      s += __shfl_xor(s, 4); s += __shfl_xor(s, 8);
      if (cid == 0) sRed[wgn][row_local] = s;
    }
  }
  __syncthreads();
  if (tid < 128) atomicAdd(&scores[r0 + tid], sRed[0][tid] + sRed[1][tid]);
}

// ---------------- K3: softmax over L per n
__global__ void softmax_k(const float* __restrict__ scores,
                          float* __restrict__ alpha) {
  const int n = blockIdx.x, tid = threadIdx.x;
  __shared__ float red[8];
  float s = (tid < LQ) ? scores[n * LQ + tid] : -1e30f;
  float m = s;
  for (int o = 32; o; o >>= 1) m = fmaxf(m, __shfl_xor(m, o));
  if ((tid & 63) == 0) red[tid >> 6] = m;
  __syncthreads();
  m = fmaxf(fmaxf(red[0], red[1]), fmaxf(red[2], red[3]));
  float e = (tid < LQ) ? __expf(s - m) : 0.f;
  float t = e;
  for (int o = 32; o; o >>= 1) t += __shfl_xor(t, o);
  if ((tid & 63) == 0) red[4 + (tid >> 6)] = t;
  __syncthreads();
  t = red[4] + red[5] + red[6] + red[7];
  if (tid < LQ) alpha[n * LQ + tid] = e / t;
}

// ---------------- K4: weighted_feature[n][d] = sum_l alpha[l]*feature[n][l][d]
__global__ void wsum_k(const float* __restrict__ feature,
                       const float* __restrict__ alpha,
                       float* __restrict__ out) {
  const int n = blockIdx.x >> 1, half = blockIdx.x & 1;
  const int tid = threadIdx.x;
  __shared__ float al[LQ];
  if (tid < LQ) al[tid] = alpha[n * LQ + tid];
  __syncthreads();
  const float* fp = feature + (size_t)n * LQ * DDIM + half * 1024 + tid * 4;
  float4 acc = {0.f, 0.f, 0.f, 0.f};
  #pragma unroll 8
  for (int l = 0; l < LQ; l++) {
    float a = al[l];
    float4 f = *(const float4*)(fp + (size_t)l * DDIM);
    acc.x = fmaf(a, f.x, acc.x); acc.y = fmaf(a, f.y, acc.y);
    acc.z = fmaf(a, f.z, acc.z); acc.w = fmaf(a, f.w, acc.w);
  }
  *(float4*)(out + n * DDIM + half * 1024 + tid * 4) = acc;
}

extern "C" void kernel_launch(void* const* d_in, const int* in_sizes, int n_in,
                              void* d_out, int out_size, void* d_ws, size_t ws_size,
                              hipStream_t stream) {
  const float* feature = (const float*)d_in[0];
  const float* prev_h  = (const float*)d_in[1];
  const float* W_enc   = (const float*)d_in[2];
  const float* b_enc   = (const float*)d_in[3];
  const float* W_dec   = (const float*)d_in[4];
  const float* b_dec   = (const float*)d_in[5];
  const float* W_tot   = (const float*)d_in[6];
  // d_in[7] = b_tot: softmax-invariant, unused

  float* out   = (float*)d_out;
  float* wf    = out;
  float* alpha = out + WF_N;

  char* ws = (char*)d_ws;
  u16*   Bst    = (u16*)ws;                                 // 2 MB
  float* att2   = (float*)(ws + (2u << 20));                // 512 KB
  float* scores = (float*)(ws + (2u << 20) + (512u << 10)); // 200704 B

  prep_k<<<772, 256, 0, stream>>>(W_enc, Bst, prev_h, W_dec, b_dec, b_enc,
                                  att2, scores);
  score_gemm_k<<<1568, 256, 0, stream>>>(feature, Bst, att2, W_tot, scores);
  softmax_k<<<256, 256, 0, stream>>>(scores, alpha);
  wsum_k<<<512, 256, 0, stream>>>(feature, alpha, wf);
}